// Round 7
// baseline (204.683 us; speedup 1.0000x reference)
//
#include <hip/hip_runtime.h>
#include <hip/hip_bf16.h>

#define B_   2
#define N_   2048
#define C_   1152
#define NH   16
#define HD   72
#define HDP  96    // padded head dim for QK^T (3 x K=32)
#define HDV  80    // padded head dim for PV (5 x 16)
#define KQKV 3456
#define KROW 104   // Ks LDS row stride (96 data + 8 pad shorts) -> 2-way reads
#define VROW 72    // Vs LDS row stride (64 data + 8 pad shorts) -> 2-way reads
#define KVB  64    // keys per attention tile (double-buffered)

typedef __attribute__((ext_vector_type(8))) short bf16x8;
typedef __attribute__((ext_vector_type(4))) float f32x4;

__device__ __forceinline__ short f2bf(float f) {
  union { float fv; unsigned int u; } v; v.fv = f;
  unsigned int r = v.u + 0x7fffu + ((v.u >> 16) & 1u);
  return (short)(r >> 16);
}

__device__ __forceinline__ float bf2f(short s) {
  union { unsigned u; float f; } v; v.u = ((unsigned)(unsigned short)s) << 16;
  return v.f;
}

__device__ __forceinline__ unsigned pack_bf16(float a, float b) {
  union { __hip_bfloat162 h; unsigned u; } c;
  c.h = __float22bfloat162_rn(make_float2(a, b));  // x=low=a, y=high=b
  return c.u;
}

__device__ __forceinline__ void gload_lds16(const short* g, short* l) {
  __builtin_amdgcn_global_load_lds(
      (const __attribute__((address_space(1))) unsigned int*)g,
      (__attribute__((address_space(3))) unsigned int*)l, 16, 0, 0);
}

// ---------------- elementwise f32 -> bf16 (vectorized x4) ----------------
__global__ void cvt_bf16(const float* __restrict__ in, short* __restrict__ out, int n4) {
  int i = blockIdx.x * 256 + threadIdx.x;
  if (i < n4) {
    float4 v = ((const float4*)in)[i];
    short4 s;
    s.x = f2bf(v.x); s.y = f2bf(v.y); s.z = f2bf(v.z); s.w = f2bf(v.w);
    ((short4*)out)[i] = s;
  }
}

// ---------------- transpose + convert: src (R x Cc f32) -> dst (Cc x R bf16) ----------------
__global__ void transpose_cvt(const float* __restrict__ src, short* __restrict__ dst,
                              int R, int Cc) {
  __shared__ float tile[32][33];
  const int c0 = blockIdx.x * 32, r0 = blockIdx.y * 32;
  const int tx = threadIdx.x, ty = threadIdx.y;  // 32 x 8
  for (int i = ty; i < 32; i += 8)
    tile[i][tx] = src[(long)(r0 + i) * Cc + c0 + tx];
  __syncthreads();
  for (int i = ty; i < 32; i += 8)
    dst[(long)(c0 + i) * R + r0 + tx] = f2bf(tile[tx][i]);
}

// ---------------- GEMM: A (MxK bf16 rm) * Bt (NxK bf16 rm)^T -> C (MxN), opt bias ----------------
// 2-phase double-buffered staging: STAGE(t+1) issued before compute(t), one
// vmcnt(0)+barrier per K-step. XCD-bijective block swizzle (nwg % 8 == 0).
template<bool BIAS, bool OBF>
__global__ __launch_bounds__(256, 2) void gemm_bt(
    const short* __restrict__ A, const short* __restrict__ Bt,
    void* __restrict__ Cv, const float* __restrict__ bias,
    int M, int N, int K) {
  __shared__ __align__(16) short As[2][128 * 32];
  __shared__ __align__(16) short Bs[2][128 * 32];
  const int t = threadIdx.x;
  const int lane = t & 63, wid = t >> 6;
  const int fr = lane & 15, fq = lane >> 4;

  int lin = blockIdx.y * gridDim.x + blockIdx.x;
  const int q8 = (int)(gridDim.x * gridDim.y) >> 3;
  lin = (lin & 7) * q8 + (lin >> 3);
  const int bm = lin / (int)gridDim.x;
  const int bn = lin - bm * (int)gridDim.x;

  const int wr = (wid >> 1) * 64, wc = (wid & 1) * 64;

  const int srow = t >> 2;
  const int scol = (t & 3) * 8;
  const short* Ag = A + (long)(bm * 128 + srow) * K + scol;
  const short* Bg = Bt + (long)(bn * 128 + srow) * K + scol;

  f32x4 acc[4][4] = {};

  auto STAGE = [&](int kt, int bufi) {
    gload_lds16(Ag + kt * 32,                &As[bufi][t * 8]);
    gload_lds16(Ag + kt * 32 + (long)64 * K, &As[bufi][2048 + t * 8]);
    gload_lds16(Bg + kt * 32,                &Bs[bufi][t * 8]);
    gload_lds16(Bg + kt * 32 + (long)64 * K, &Bs[bufi][2048 + t * 8]);
  };

  const int NKT = K / 32;
  STAGE(0, 0);
  asm volatile("s_waitcnt vmcnt(0)" ::: "memory");
  __syncthreads();

  for (int kt = 0; kt < NKT; ++kt) {
    const int cur = kt & 1;
    if (kt + 1 < NKT) STAGE(kt + 1, cur ^ 1);

    bf16x8 af[4], bf[4];
    #pragma unroll
    for (int i = 0; i < 4; ++i)
      af[i] = *(const bf16x8*)(&As[cur][(wr + i * 16 + fr) * 32 + fq * 8]);
    #pragma unroll
    for (int j = 0; j < 4; ++j)
      bf[j] = *(const bf16x8*)(&Bs[cur][(wc + j * 16 + fr) * 32 + fq * 8]);
    #pragma unroll
    for (int i = 0; i < 4; ++i)
      #pragma unroll
      for (int j = 0; j < 4; ++j)
        acc[i][j] = __builtin_amdgcn_mfma_f32_16x16x32_bf16(af[i], bf[j], acc[i][j], 0, 0, 0);

    asm volatile("s_waitcnt vmcnt(0)" ::: "memory");
    __syncthreads();
  }

  #pragma unroll
  for (int i = 0; i < 4; ++i) {
    #pragma unroll
    for (int j = 0; j < 4; ++j) {
      const long row0 = (long)bm * 128 + wr + i * 16 + fq * 4;
      const int col = bn * 128 + wc + j * 16 + fr;
      const float bv = BIAS ? bias[col] : 0.f;
      #pragma unroll
      for (int r = 0; r < 4; ++r) {
        const float val = acc[i][j][r] + bv;
        if constexpr (OBF)
          ((short*)Cv)[(row0 + r) * (long)N + col] = f2bf(val);
        else
          ((float*)Cv)[(row0 + r) * (long)N + col] = val;
      }
    }
  }
}

// ---------------- RoPE + repack (bf16 QKV input) ----------------
// Q: rope'd and scaled by (1/sqrt(72))*log2(e)  [exp2-based softmax downstream]
// K: rope'd. V: transposed to (b,h,d,n) with columns permuted within each
// 32-key group by pi(c) = ((c>>2)&1)*16 + ((c>>3)&3)*4 + (c&3) so the attn
// PV A-fragment is lane-local.
__global__ __launch_bounds__(256) void rope_pack(
    const short* __restrict__ QKV, short* __restrict__ Qp,
    short* __restrict__ Kp, short* __restrict__ Vt) {
  const int blk = blockIdx.x;
  const int nt = blk & 15;
  const int h = (blk >> 4) & 15;
  const int b = blk >> 8;
  const int t = threadIdx.x;
  const int n0 = nt * 128;
  const float qscale = 0.17002324f;  // (1/sqrt(72)) * log2(e)
  const float PI = 3.14159265358979323846f;

  for (int which = 0; which < 2; ++which) {
    short* dst = which ? Kp : Qp;
    const float sc = which ? 1.0f : qscale;
    for (int idx = t; idx < 128 * 48; idx += 256) {
      const int r = idx / 48;
      const int p = idx - r * 48;   // pair index: d = 2p, 2p+1
      const int n = n0 + r;
      float vx = 0.f, vy = 0.f;
      if (p < 36) {
        short2 v2 = *(const short2*)(QKV + ((long)(b * N_ + n)) * KQKV + which * C_ + h * HD + 2 * p);
        vx = bf2f(v2.x); vy = bf2f(v2.y);
      }
      float o0 = vx, o1 = vy;
      if (p < 24) {
        float pos;
        if (p < 8)       pos = -1.f + (2.f / 7.f)  * (float)(n >> 8);
        else if (p < 16) pos = -1.f + (2.f / 15.f) * (float)((n >> 4) & 15);
        else             pos = -1.f + (2.f / 15.f) * (float)(n & 15);
        const float base = (1.f + (127.f / 7.f) * (float)(p & 7)) * PI;
        const float f = pos * base;
        const float cs = cosf(f), sn = sinf(f);
        o0 = vx * cs - vy * sn;
        o1 = vy * cs + vx * sn;
      }
      short2 ov; ov.x = f2bf(o0 * sc); ov.y = f2bf(o1 * sc);
      *(short2*)(dst + (((long)(b * NH + h)) * N_ + n) * HDP + 2 * p) = ov;
    }
  }

  __shared__ short vt[128][82];
  for (int idx = t; idx < 128 * 40; idx += 256) {
    const int r = idx / 40, p = idx - r * 40;  // d = 2p, 2p+1 (HDV=80 -> 40 pairs)
    short2 v2; v2.x = 0; v2.y = 0;
    if (p < 36)
      v2 = *(const short2*)(QKV + ((long)(b * N_ + n0 + r)) * KQKV + 2 * C_ + h * HD + 2 * p);
    *(short2*)(&vt[r][2 * p]) = v2;
  }
  __syncthreads();
  for (int idx = t; idx < HDV * 128; idx += 256) {
    const int d = idx >> 7, nn = idx & 127;
    const int c = nn & 31;
    const int nsrc = (nn & 96) | (((c >> 2) & 1) * 16 + ((c >> 3) & 3) * 4 + (c & 3));
    Vt[(((long)(b * NH + h)) * HDV + d) * N_ + n0 + nn] = vt[nsrc][d];
  }
}

// ---------------- flash attention ----------------
// 64 q-rows PER WAVE (4 q-frag blocks): each K/V ds_read feeds 4 MFMA instead
// of 2, halving LDS-pipe pressure. 256 blocks = 1 block/CU (4 waves, 1/SIMD);
// ILP from 4 independent q-chains replaces TLP. Swapped QK^T, lane-local P via
// pi-permuted V, fixed-max exp2 softmax, 64-key double-buffered 2-phase tiles,
// XCD-bijective swizzle (same-head q-tiles share an XCD's L2).
__global__ __launch_bounds__(256, 1) void attn(
    const short* __restrict__ Qp, const short* __restrict__ Kp,
    const short* __restrict__ Vt, short* __restrict__ Aproj) {
  __shared__ __align__(16) short Ks[2][KVB * KROW];  // 2 x 13 KB
  __shared__ __align__(16) short Vs[2][HDV * VROW];  // 2 x 11.25 KB
  int blk = blockIdx.x;
  blk = (blk & 7) * 32 + (blk >> 3);   // 256 % 8 == 0 -> bijective
  const int qt = blk & 7;              // 8 q-tiles of 256 rows
  const int h = (blk >> 3) & 15;
  const int b = blk >> 7;
  const int t = threadIdx.x, lane = t & 63, wid = t >> 6;
  const int fr = lane & 15, fq = lane >> 4;

  const long bh = (long)(b * NH + h);
  const short* Qg = Qp + (bh * N_ + qt * 256) * HDP;
  const short* Kg = Kp + bh * N_ * HDP;
  const short* Vg = Vt + bh * HDV * N_;

  // per-lane staging source offsets (prologue-only division)
  // K tile: 64 rows x 13 chunks (12 data + 1 pad) = 832 chunks of 16B
  int koff[4];
  #pragma unroll
  for (int it = 0; it < 4; ++it) {
    const int p = it * 256 + t;
    const int row = p / 13, c = p - row * 13;
    koff[it] = row * HDP + (c < 12 ? c * 8 : 0);
  }
  // V tile: 80 rows x 9 chunks (8 data + 1 pad) = 720 chunks
  int voff[3];
  #pragma unroll
  for (int it = 0; it < 3; ++it) {
    const int p = it * 256 + t;
    const int row = p / 9, c = p - row * 9;
    voff[it] = row * N_ + (c < 8 ? c * 8 : 0);
  }

  // Q fragments in registers for the whole kernel (B-operand; q = i*16+fr)
  bf16x8 qf[4][3];
  #pragma unroll
  for (int i = 0; i < 4; ++i)
    #pragma unroll
    for (int kk = 0; kk < 3; ++kk)
      qf[i][kk] = *(const bf16x8*)(Qg + (wid * 64 + i * 16 + fr) * HDP + kk * 32 + fq * 8);

  f32x4 accO[4][5] = {};
  float l_[4] = {0.f, 0.f, 0.f, 0.f};

  auto STAGE = [&](int kt, int bufi) {
    const short* Ksrc = Kg + (long)kt * KVB * HDP;
    const short* Vsrc = Vg + kt * KVB;
    short* KD = &Ks[bufi][0];
    short* VD = &Vs[bufi][0];
    #pragma unroll
    for (int it = 0; it < 4; ++it)
      if (it < 3 || t < 64)
        gload_lds16(Ksrc + koff[it], KD + (it * 256 + t) * 8);
    #pragma unroll
    for (int it = 0; it < 3; ++it)
      if (it < 2 || t < 208)
        gload_lds16(Vsrc + voff[it], VD + (it * 256 + t) * 8);
  };

  STAGE(0, 0);
  asm volatile("s_waitcnt vmcnt(0)" ::: "memory");
  __syncthreads();

  for (int kt = 0; kt < 32; ++kt) {
    const int cur = kt & 1;
    if (kt < 31) STAGE(kt + 1, cur ^ 1);   // prefetch overlaps compute below
    const short* KsC = &Ks[cur][0];
    const short* VsC = &Vs[cur][0];

    // S^T = K Q^T : each kf feeds 4 q-frags
    f32x4 s[4][4] = {};
    __builtin_amdgcn_s_setprio(1);
    #pragma unroll
    for (int j = 0; j < 4; ++j) {
      #pragma unroll
      for (int kk = 0; kk < 3; ++kk) {
        bf16x8 kf = *(const bf16x8*)(KsC + (j * 16 + fr) * KROW + (kk * 4 + fq) * 8);
        #pragma unroll
        for (int i = 0; i < 4; ++i)
          s[i][j] = __builtin_amdgcn_mfma_f32_16x16x32_bf16(kf, qf[i][kk], s[i][j], 0, 0, 0);
      }
    }
    __builtin_amdgcn_s_setprio(0);

    // fixed-max softmax: p = 2^s (log2e folded into Q scale); l lane-partial
    #pragma unroll
    for (int i = 0; i < 4; ++i) {
      float psum = 0.f;
      #pragma unroll
      for (int j = 0; j < 4; ++j)
        #pragma unroll
        for (int r = 0; r < 4; ++r) {
          const float p = __builtin_amdgcn_exp2f(s[i][j][r]);
          s[i][j][r] = p;
          psum += p;
        }
      l_[i] += psum;
    }

    // O += P V : A-frag lane-local (keys permuted), vf feeds 4 q-frags
    __builtin_amdgcn_s_setprio(1);
    #pragma unroll
    for (int g = 0; g < 2; ++g) {
      union { unsigned u[4]; bf16x8 v; } pf[4];
      #pragma unroll
      for (int i = 0; i < 4; ++i) {
        pf[i].u[0] = pack_bf16(s[i][2 * g][0],     s[i][2 * g][1]);
        pf[i].u[1] = pack_bf16(s[i][2 * g][2],     s[i][2 * g][3]);
        pf[i].u[2] = pack_bf16(s[i][2 * g + 1][0], s[i][2 * g + 1][1]);
        pf[i].u[3] = pack_bf16(s[i][2 * g + 1][2], s[i][2 * g + 1][3]);
      }
      #pragma unroll
      for (int jd = 0; jd < 5; ++jd) {
        bf16x8 vf = *(const bf16x8*)(VsC + (jd * 16 + fr) * VROW + (g * 4 + fq) * 8);
        #pragma unroll
        for (int i = 0; i < 4; ++i)
          accO[i][jd] = __builtin_amdgcn_mfma_f32_16x16x32_bf16(pf[i].v, vf, accO[i][jd], 0, 0, 0);
      }
    }
    __builtin_amdgcn_s_setprio(0);
    asm volatile("s_waitcnt vmcnt(0)" ::: "memory");
    __syncthreads();
  }

  // epilogue: reduce l across the 4 key-lane groups, then normalize
  #pragma unroll
  for (int i = 0; i < 4; ++i) {
    l_[i] += __shfl_xor(l_[i], 16);
    l_[i] += __shfl_xor(l_[i], 32);
  }
  #pragma unroll
  for (int i = 0; i < 4; ++i) {
    const float linv = 1.f / l_[i];
    float li[4];
    #pragma unroll
    for (int r = 0; r < 4; ++r) li[r] = __shfl(linv, fq * 4 + r);
    #pragma unroll
    for (int r = 0; r < 4; ++r) {
      const long n = qt * 256 + wid * 64 + i * 16 + fq * 4 + r;
      #pragma unroll
      for (int jd = 0; jd < 5; ++jd) {
        const int d = jd * 16 + fr;
        if (d < HD)
          Aproj[((long)b * N_ + n) * C_ + h * HD + d] = f2bf(accO[i][jd][r] * li[r]);
      }
    }
  }
}

extern "C" void kernel_launch(void* const* d_in, const int* in_sizes, int n_in,
                              void* d_out, int out_size, void* d_ws, size_t ws_size,
                              hipStream_t stream) {
  const float* x     = (const float*)d_in[0];
  const float* Wqkv  = (const float*)d_in[1];
  const float* Wproj = (const float*)d_in[2];
  const float* bproj = (const float*)d_in[3];
  float* out = (float*)d_out;

  char* ws = (char*)d_ws;
  short* QKVb = (short*)ws;        size_t off = (size_t)4096 * 3456 * 2;
  short* xb  = (short*)(ws + off);  off += (size_t)4096 * 1152 * 2;
  short* Wt  = (short*)(ws + off);  off += (size_t)3456 * 1152 * 2;
  short* Wpt = (short*)(ws + off);  off += (size_t)1152 * 1152 * 2;
  short* Qp  = (short*)(ws + off);  off += (size_t)B_ * NH * N_ * HDP * 2;
  short* Kp  = (short*)(ws + off);  off += (size_t)B_ * NH * N_ * HDP * 2;
  short* Vt  = (short*)(ws + off);  off += (size_t)B_ * NH * HDV * N_ * 2;
  short* Ap  = (short*)(ws + off);  off += (size_t)4096 * 1152 * 2;

  cvt_bf16<<<(4096 * 1152 / 4 + 255) / 256, 256, 0, stream>>>(x, xb, 4096 * 1152 / 4);
  transpose_cvt<<<dim3(3456 / 32, 1152 / 32), dim3(32, 8), 0, stream>>>(Wqkv, Wt, 1152, 3456);
  transpose_cvt<<<dim3(1152 / 32, 1152 / 32), dim3(32, 8), 0, stream>>>(Wproj, Wpt, 1152, 1152);
  gemm_bt<false, true><<<dim3(3456 / 128, 4096 / 128), 256, 0, stream>>>(
      xb, Wt, (void*)QKVb, nullptr, 4096, 3456, 1152);
  rope_pack<<<B_ * NH * (N_ / 128), 256, 0, stream>>>(QKVb, Qp, Kp, Vt);
  attn<<<B_ * NH * (N_ / 256), 256, 0, stream>>>(Qp, Kp, Vt, Ap);
  gemm_bt<true, false><<<dim3(1152 / 128, 4096 / 128), 256, 0, stream>>>(
      Ap, Wpt, (void*)out, bproj, 4096, 1152, 1152);
}

// Round 8
// 190.818 us; speedup vs baseline: 1.0727x; 1.0727x over previous
//
#include <hip/hip_runtime.h>
#include <hip/hip_bf16.h>

#define B_   2
#define N_   2048
#define C_   1152
#define NH   16
#define HD   72
#define HDP  96    // padded head dim for QK^T (3 x K=32)
#define HDV  80    // padded head dim for PV (5 x 16)
#define QSTR 3584  // padded QKV row stride (3456 -> 14 x 256)
#define KROW 104   // Ks LDS row stride (96 data + 8 pad shorts) -> 2-way reads
#define VROW 72    // Vs LDS row stride (64 data + 8 pad shorts) -> 2-way reads
#define KVB  64    // keys per attention tile (double-buffered)

typedef __attribute__((ext_vector_type(8))) short bf16x8;
typedef __attribute__((ext_vector_type(4))) float f32x4;

__device__ __forceinline__ short f2bf(float f) {
  union { float fv; unsigned int u; } v; v.fv = f;
  unsigned int r = v.u + 0x7fffu + ((v.u >> 16) & 1u);
  return (short)(r >> 16);
}

__device__ __forceinline__ float bf2f(short s) {
  union { unsigned u; float f; } v; v.u = ((unsigned)(unsigned short)s) << 16;
  return v.f;
}

__device__ __forceinline__ unsigned pack_bf16(float a, float b) {
  union { __hip_bfloat162 h; unsigned u; } c;
  c.h = __float22bfloat162_rn(make_float2(a, b));  // x=low=a, y=high=b
  return c.u;
}

__device__ __forceinline__ void gload_lds16(const short* g, short* l) {
  __builtin_amdgcn_global_load_lds(
      (const __attribute__((address_space(1))) unsigned int*)g,
      (__attribute__((address_space(3))) unsigned int*)l, 16, 0, 0);
}

// ---------------- elementwise f32 -> bf16 (vectorized x4) ----------------
__global__ void cvt_bf16(const float* __restrict__ in, short* __restrict__ out, int n4) {
  int i = blockIdx.x * 256 + threadIdx.x;
  if (i < n4) {
    float4 v = ((const float4*)in)[i];
    short4 s;
    s.x = f2bf(v.x); s.y = f2bf(v.y); s.z = f2bf(v.z); s.w = f2bf(v.w);
    ((short4*)out)[i] = s;
  }
}

// ---------------- transpose + convert: src (R x Cc f32) -> dst (Np x R bf16), zero-pad rows >= Cc ----
__global__ void transpose_cvt(const float* __restrict__ src, short* __restrict__ dst,
                              int R, int Cc, int Np) {
  __shared__ float tile[32][33];
  const int c0 = blockIdx.x * 32, r0 = blockIdx.y * 32;
  const int tx = threadIdx.x, ty = threadIdx.y;  // 32 x 8
  for (int i = ty; i < 32; i += 8)
    tile[i][tx] = (c0 + tx < Cc) ? src[(long)(r0 + i) * Cc + c0 + tx] : 0.f;
  __syncthreads();
  for (int i = ty; i < 32; i += 8)
    dst[(long)(c0 + i) * R + r0 + tx] = f2bf(tile[tx][i]);
}

// ---------------- GEMM 128^2 (m97-structure, counted-vmcnt raw-barrier dbuf) ----------------
template<bool BIAS, bool OBF>
__global__ __launch_bounds__(256, 2) void gemm_bt(
    const short* __restrict__ A, const short* __restrict__ Bt,
    void* __restrict__ Cv, const float* __restrict__ bias,
    int M, int N, int K) {
  __shared__ __align__(16) short As[2][128 * 32];
  __shared__ __align__(16) short Bs[2][128 * 32];
  const int t = threadIdx.x;
  const int lane = t & 63, wid = t >> 6;
  const int fr = lane & 15, fq = lane >> 4;

  int lin = blockIdx.y * gridDim.x + blockIdx.x;
  const int q8 = (int)(gridDim.x * gridDim.y) >> 3;
  lin = (lin & 7) * q8 + (lin >> 3);
  const int bm = lin / (int)gridDim.x;
  const int bn = lin - bm * (int)gridDim.x;

  const int wr = (wid >> 1) * 64, wc = (wid & 1) * 64;

  const int srow = t >> 2;
  const int scol = (t & 3) * 8;
  const short* Ag = A + (long)(bm * 128 + srow) * K + scol;
  const short* Bg = Bt + (long)(bn * 128 + srow) * K + scol;

  f32x4 acc[4][4] = {};

  auto STAGE = [&](int kt, int bufi) {
    gload_lds16(Ag + kt * 32,                &As[bufi][t * 8]);
    gload_lds16(Ag + kt * 32 + (long)64 * K, &As[bufi][2048 + t * 8]);
    gload_lds16(Bg + kt * 32,                &Bs[bufi][t * 8]);
    gload_lds16(Bg + kt * 32 + (long)64 * K, &Bs[bufi][2048 + t * 8]);
  };

  const int NKT = K / 32;
  STAGE(0, 0);

  for (int kt = 0; kt < NKT; ++kt) {
    const int cur = kt & 1;
    if (kt + 1 < NKT) {
      STAGE(kt + 1, cur ^ 1);
      asm volatile("s_waitcnt vmcnt(4)" ::: "memory");  // oldest 4 (this tile) landed
    } else {
      asm volatile("s_waitcnt vmcnt(0)" ::: "memory");
    }
    __builtin_amdgcn_s_barrier();

    bf16x8 af[4], bf[4];
    #pragma unroll
    for (int i = 0; i < 4; ++i)
      af[i] = *(const bf16x8*)(&As[cur][(wr + i * 16 + fr) * 32 + fq * 8]);
    #pragma unroll
    for (int j = 0; j < 4; ++j)
      bf[j] = *(const bf16x8*)(&Bs[cur][(wc + j * 16 + fr) * 32 + fq * 8]);
    __builtin_amdgcn_s_setprio(1);
    #pragma unroll
    for (int i = 0; i < 4; ++i)
      #pragma unroll
      for (int j = 0; j < 4; ++j)
        acc[i][j] = __builtin_amdgcn_mfma_f32_16x16x32_bf16(af[i], bf[j], acc[i][j], 0, 0, 0);
    __builtin_amdgcn_s_setprio(0);
    __builtin_amdgcn_s_barrier();  // reads of cur done before next STAGE overwrites it
  }

  #pragma unroll
  for (int i = 0; i < 4; ++i) {
    #pragma unroll
    for (int j = 0; j < 4; ++j) {
      const long row0 = (long)bm * 128 + wr + i * 16 + fq * 4;
      const int col = bn * 128 + wc + j * 16 + fr;
      const float bv = BIAS ? bias[col] : 0.f;
      #pragma unroll
      for (int r = 0; r < 4; ++r) {
        const float val = acc[i][j][r] + bv;
        if constexpr (OBF)
          ((short*)Cv)[(row0 + r) * (long)N + col] = f2bf(val);
        else
          ((float*)Cv)[(row0 + r) * (long)N + col] = val;
      }
    }
  }
}

// ---------------- GEMM 256^2, BK=64, 8 waves, 4-phase counted-vmcnt schedule ----------------
// LDS [256][64] linear rows; chunk-XOR swizzle phys = lc ^ (row&7) applied on
// the global SOURCE (linear gload_lds dest, rule 21) and on ds_read addresses
// (per-lane constant fr&7). Phases: (mh,nh) quadrants of the wave's 128x64
// output; 16 MFMA + <=12 ds_read + 2 staging loads per phase; one vmcnt(2)
// per K-tile (prefetch stays in flight across raw barriers). Output bf16.
__global__ __launch_bounds__(512, 2) void gemm_bt256(
    const short* __restrict__ A, const short* __restrict__ Bt,
    short* __restrict__ Cv, int M, int N, int K) {
  __shared__ __align__(16) short As[2][256 * 64];  // 2 x 32 KB
  __shared__ __align__(16) short Bs[2][256 * 64];  // 2 x 32 KB
  const int t = threadIdx.x;
  const int lane = t & 63, wid = t >> 6;
  const int fr = lane & 15, fq = lane >> 4;
  const int wm = wid >> 2, wn = wid & 3;   // 2M x 4N wave grid
  const int rx = fr & 7;                   // read-side chunk XOR

  int lin = blockIdx.y * gridDim.x + blockIdx.x;
  const int q8 = (int)(gridDim.x * gridDim.y) >> 3;
  lin = (lin & 7) * q8 + (lin >> 3);
  const int bm = lin / (int)gridDim.x;
  const int bn = lin - bm * (int)gridDim.x;

  // staging source offsets: 4 rounds/matrix/K-tile; chunk p = r*512+t
  // row = p>>3, phys chunk = p&7, logical = phys ^ (row&7)
  int soff[4];
  #pragma unroll
  for (int r = 0; r < 4; ++r) {
    const int p = r * 512 + t;
    const int row = p >> 3, pc = p & 7;
    soff[r] = row * K + (pc ^ (row & 7)) * 8;
  }
  const short* Ag = A + (long)bm * 256 * K;
  const short* Bg = Bt + (long)bn * 256 * K;

  f32x4 acc[8][4] = {};

  // phase ph issues rounds 2ph, 2ph+1 (rounds 0-3 = A, 4-7 = B)
  auto STG2 = [&](int kt, int bufi, int ph) {
    #pragma unroll
    for (int k2 = 0; k2 < 2; ++k2) {
      const int r = ph * 2 + k2;
      if (r < 4)
        gload_lds16(Ag + soff[r] + kt * 64, &As[bufi][(r * 512 + t) * 8]);
      else
        gload_lds16(Bg + soff[r - 4] + kt * 64, &Bs[bufi][((r - 4) * 512 + t) * 8]);
    }
  };

  const int NKT = K / 64;
  #pragma unroll
  for (int ph = 0; ph < 4; ++ph) STG2(0, 0, ph);

  for (int kt = 0; kt < NKT; ++kt) {
    const int cur = kt & 1;
    const bool pre = (kt + 1 < NKT);
    const short* Ac = &As[cur][0];
    const short* Bc = &Bs[cur][0];
    bf16x8 af[4][2], bf0[2][2], bf1[2][2];

    // ---- phase 0: quadrant (mh0, nh0) ----
    if (pre) {
      STG2(kt + 1, cur ^ 1, 0);
      asm volatile("s_waitcnt vmcnt(2)" ::: "memory");  // oldest 8 (this tile) landed
    } else {
      asm volatile("s_waitcnt vmcnt(0)" ::: "memory");
    }
    __builtin_amdgcn_s_barrier();
    #pragma unroll
    for (int i = 0; i < 4; ++i)
      #pragma unroll
      for (int kk = 0; kk < 2; ++kk)
        af[i][kk] = *(const bf16x8*)(Ac + (wm * 128 + i * 16 + fr) * 64 + (((kk * 4 + fq) ^ rx) * 8));
    #pragma unroll
    for (int j = 0; j < 2; ++j)
      #pragma unroll
      for (int kk = 0; kk < 2; ++kk)
        bf0[j][kk] = *(const bf16x8*)(Bc + (wn * 64 + j * 16 + fr) * 64 + (((kk * 4 + fq) ^ rx) * 8));
    __builtin_amdgcn_s_setprio(1);
    #pragma unroll
    for (int i = 0; i < 4; ++i)
      #pragma unroll
      for (int j = 0; j < 2; ++j)
        #pragma unroll
        for (int kk = 0; kk < 2; ++kk)
          acc[i][j] = __builtin_amdgcn_mfma_f32_16x16x32_bf16(af[i][kk], bf0[j][kk], acc[i][j], 0, 0, 0);
    __builtin_amdgcn_s_setprio(0);
    __builtin_amdgcn_s_barrier();

    // ---- phase 1: (mh0, nh1) ----
    if (pre) STG2(kt + 1, cur ^ 1, 1);
    #pragma unroll
    for (int j = 0; j < 2; ++j)
      #pragma unroll
      for (int kk = 0; kk < 2; ++kk)
        bf1[j][kk] = *(const bf16x8*)(Bc + (wn * 64 + 32 + j * 16 + fr) * 64 + (((kk * 4 + fq) ^ rx) * 8));
    __builtin_amdgcn_s_setprio(1);
    #pragma unroll
    for (int i = 0; i < 4; ++i)
      #pragma unroll
      for (int j = 0; j < 2; ++j)
        #pragma unroll
        for (int kk = 0; kk < 2; ++kk)
          acc[i][2 + j] = __builtin_amdgcn_mfma_f32_16x16x32_bf16(af[i][kk], bf1[j][kk], acc[i][2 + j], 0, 0, 0);
    __builtin_amdgcn_s_setprio(0);
    __builtin_amdgcn_s_barrier();

    // ---- phase 2: (mh1, nh0) ----
    if (pre) STG2(kt + 1, cur ^ 1, 2);
    #pragma unroll
    for (int i = 0; i < 4; ++i)
      #pragma unroll
      for (int kk = 0; kk < 2; ++kk)
        af[i][kk] = *(const bf16x8*)(Ac + (wm * 128 + 64 + i * 16 + fr) * 64 + (((kk * 4 + fq) ^ rx) * 8));
    __builtin_amdgcn_s_setprio(1);
    #pragma unroll
    for (int i = 0; i < 4; ++i)
      #pragma unroll
      for (int j = 0; j < 2; ++j)
        #pragma unroll
        for (int kk = 0; kk < 2; ++kk)
          acc[4 + i][j] = __builtin_amdgcn_mfma_f32_16x16x32_bf16(af[i][kk], bf0[j][kk], acc[4 + i][j], 0, 0, 0);
    __builtin_amdgcn_s_setprio(0);
    __builtin_amdgcn_s_barrier();

    // ---- phase 3: (mh1, nh1) ----
    if (pre) STG2(kt + 1, cur ^ 1, 3);
    __builtin_amdgcn_s_setprio(1);
    #pragma unroll
    for (int i = 0; i < 4; ++i)
      #pragma unroll
      for (int j = 0; j < 2; ++j)
        #pragma unroll
        for (int kk = 0; kk < 2; ++kk)
          acc[4 + i][2 + j] = __builtin_amdgcn_mfma_f32_16x16x32_bf16(af[i][kk], bf1[j][kk], acc[4 + i][2 + j], 0, 0, 0);
    __builtin_amdgcn_s_setprio(0);
    __builtin_amdgcn_s_barrier();
  }

  #pragma unroll
  for (int mi = 0; mi < 8; ++mi) {
    #pragma unroll
    for (int j = 0; j < 4; ++j) {
      const long row0 = (long)bm * 256 + wm * 128 + (mi >> 2) * 64 + (mi & 3) * 16 + fq * 4;
      const int col = bn * 256 + wn * 64 + j * 16 + fr;
      #pragma unroll
      for (int r = 0; r < 4; ++r)
        Cv[(row0 + r) * (long)N + col] = f2bf(acc[mi][j][r]);
    }
  }
}

// ---------------- RoPE + repack (bf16 QKV input, stride QSTR) ----------------
__global__ __launch_bounds__(256) void rope_pack(
    const short* __restrict__ QKV, short* __restrict__ Qp,
    short* __restrict__ Kp, short* __restrict__ Vt) {
  const int blk = blockIdx.x;
  const int nt = blk & 15;
  const int h = (blk >> 4) & 15;
  const int b = blk >> 8;
  const int t = threadIdx.x;
  const int n0 = nt * 128;
  const float qscale = 0.17002324f;  // (1/sqrt(72)) * log2(e)
  const float PI = 3.14159265358979323846f;

  for (int which = 0; which < 2; ++which) {
    short* dst = which ? Kp : Qp;
    const float sc = which ? 1.0f : qscale;
    for (int idx = t; idx < 128 * 48; idx += 256) {
      const int r = idx / 48;
      const int p = idx - r * 48;   // pair index: d = 2p, 2p+1
      const int n = n0 + r;
      float vx = 0.f, vy = 0.f;
      if (p < 36) {
        short2 v2 = *(const short2*)(QKV + ((long)(b * N_ + n)) * QSTR + which * C_ + h * HD + 2 * p);
        vx = bf2f(v2.x); vy = bf2f(v2.y);
      }
      float o0 = vx, o1 = vy;
      if (p < 24) {
        float pos;
        if (p < 8)       pos = -1.f + (2.f / 7.f)  * (float)(n >> 8);
        else if (p < 16) pos = -1.f + (2.f / 15.f) * (float)((n >> 4) & 15);
        else             pos = -1.f + (2.f / 15.f) * (float)(n & 15);
        const float base = (1.f + (127.f / 7.f) * (float)(p & 7)) * PI;
        const float f = pos * base;
        const float cs = cosf(f), sn = sinf(f);
        o0 = vx * cs - vy * sn;
        o1 = vy * cs + vx * sn;
      }
      short2 ov; ov.x = f2bf(o0 * sc); ov.y = f2bf(o1 * sc);
      *(short2*)(dst + (((long)(b * NH + h)) * N_ + n) * HDP + 2 * p) = ov;
    }
  }

  __shared__ short vt[128][82];
  for (int idx = t; idx < 128 * 40; idx += 256) {
    const int r = idx / 40, p = idx - r * 40;
    short2 v2; v2.x = 0; v2.y = 0;
    if (p < 36)
      v2 = *(const short2*)(QKV + ((long)(b * N_ + n0 + r)) * QSTR + 2 * C_ + h * HD + 2 * p);
    *(short2*)(&vt[r][2 * p]) = v2;
  }
  __syncthreads();
  for (int idx = t; idx < HDV * 128; idx += 256) {
    const int d = idx >> 7, nn = idx & 127;
    const int c = nn & 31;
    const int nsrc = (nn & 96) | (((c >> 2) & 1) * 16 + ((c >> 3) & 3) * 4 + (c & 3));
    Vt[(((long)(b * NH + h)) * HDV + d) * N_ + n0 + nn] = vt[nsrc][d];
  }
}

// ---------------- flash attention (round-6 verbatim: 32 q/wave, 512 blocks) ----------------
__global__ __launch_bounds__(256, 3) void attn(
    const short* __restrict__ Qp, const short* __restrict__ Kp,
    const short* __restrict__ Vt, short* __restrict__ Aproj) {
  __shared__ __align__(16) short Ks[2][KVB * KROW];  // 2 x 13 KB
  __shared__ __align__(16) short Vs[2][HDV * VROW];  // 2 x 11.25 KB
  int blk = blockIdx.x;
  blk = (blk & 7) * 64 + (blk >> 3);   // 512 % 8 == 0 -> bijective
  const int qt = blk & 15;
  const int h = (blk >> 4) & 15;
  const int b = blk >> 8;
  const int t = threadIdx.x, lane = t & 63, wid = t >> 6;
  const int fr = lane & 15, fq = lane >> 4;

  const long bh = (long)(b * NH + h);
  const short* Qg = Qp + (bh * N_ + qt * 128) * HDP;
  const short* Kg = Kp + bh * N_ * HDP;
  const short* Vg = Vt + bh * HDV * N_;

  int koff[4];
  #pragma unroll
  for (int it = 0; it < 4; ++it) {
    const int p = it * 256 + t;
    const int row = p / 13, c = p - row * 13;
    koff[it] = row * HDP + (c < 12 ? c * 8 : 0);
  }
  int voff[3];
  #pragma unroll
  for (int it = 0; it < 3; ++it) {
    const int p = it * 256 + t;
    const int row = p / 9, c = p - row * 9;
    voff[it] = row * N_ + (c < 8 ? c * 8 : 0);
  }

  bf16x8 qf[2][3];
  #pragma unroll
  for (int i = 0; i < 2; ++i)
    #pragma unroll
    for (int kk = 0; kk < 3; ++kk)
      qf[i][kk] = *(const bf16x8*)(Qg + (wid * 32 + i * 16 + fr) * HDP + kk * 32 + fq * 8);

  f32x4 accO[2][5] = {};
  float l_[2] = {0.f, 0.f};

  auto STAGE = [&](int kt, int bufi) {
    const short* Ksrc = Kg + (long)kt * KVB * HDP;
    const short* Vsrc = Vg + kt * KVB;
    short* KD = &Ks[bufi][0];
    short* VD = &Vs[bufi][0];
    #pragma unroll
    for (int it = 0; it < 4; ++it)
      if (it < 3 || t < 64)
        gload_lds16(Ksrc + koff[it], KD + (it * 256 + t) * 8);
    #pragma unroll
    for (int it = 0; it < 3; ++it)
      if (it < 2 || t < 208)
        gload_lds16(Vsrc + voff[it], VD + (it * 256 + t) * 8);
  };

  STAGE(0, 0);
  asm volatile("s_waitcnt vmcnt(0)" ::: "memory");
  __syncthreads();

  for (int kt = 0; kt < 32; ++kt) {
    const int cur = kt & 1;
    if (kt < 31) STAGE(kt + 1, cur ^ 1);
    const short* KsC = &Ks[cur][0];
    const short* VsC = &Vs[cur][0];

    f32x4 s[2][4] = {};
    __builtin_amdgcn_s_setprio(1);
    #pragma unroll
    for (int j = 0; j < 4; ++j) {
      #pragma unroll
      for (int kk = 0; kk < 3; ++kk) {
        bf16x8 kf = *(const bf16x8*)(KsC + (j * 16 + fr) * KROW + (kk * 4 + fq) * 8);
        s[0][j] = __builtin_amdgcn_mfma_f32_16x16x32_bf16(kf, qf[0][kk], s[0][j], 0, 0, 0);
        s[1][j] = __builtin_amdgcn_mfma_f32_16x16x32_bf16(kf, qf[1][kk], s[1][j], 0, 0, 0);
      }
    }
    __builtin_amdgcn_s_setprio(0);

    #pragma unroll
    for (int i = 0; i < 2; ++i) {
      float psum = 0.f;
      #pragma unroll
      for (int j = 0; j < 4; ++j)
        #pragma unroll
        for (int r = 0; r < 4; ++r) {
          const float p = __builtin_amdgcn_exp2f(s[i][j][r]);
          s[i][j][r] = p;
          psum += p;
        }
      l_[i] += psum;
    }

    __builtin_amdgcn_s_setprio(1);
    #pragma unroll
    for (int g = 0; g < 2; ++g) {
      union { unsigned u[4]; bf16x8 v; } pf0, pf1;
      pf0.u[0] = pack_bf16(s[0][2 * g][0],     s[0][2 * g][1]);
      pf0.u[1] = pack_bf16(s[0][2 * g][2],     s[0][2 * g][3]);
      pf0.u[2] = pack_bf16(s[0][2 * g + 1][0], s[0][2 * g + 1][1]);
      pf0.u[3] = pack_bf16(s[0][2 * g + 1][2], s[0][2 * g + 1][3]);
      pf1.u[0] = pack_bf16(s[1][2 * g][0],     s[1][2 * g][1]);
      pf1.u[1] = pack_bf16(s[1][2 * g][2],     s[1][2 * g][3]);
      pf1.u[2] = pack_bf16(s[1][2 * g + 1][0], s[1][2 * g + 1][1]);
      pf1.u[3] = pack_bf16(s[1][2 * g + 1][2], s[1][2 * g + 1][3]);
      #pragma unroll
      for (int jd = 0; jd < 5; ++jd) {
        bf16x8 vf = *(const bf16x8*)(VsC + (jd * 16 + fr) * VROW + (g * 4 + fq) * 8);
        accO[0][jd] = __builtin_amdgcn_mfma_f32_16x16x32_bf16(pf0.v, vf, accO[0][jd], 0, 0, 0);
        accO[1][jd] = __builtin_amdgcn_mfma_f32_16x16x32_bf16(pf1.v, vf, accO[1][jd], 0, 0, 0);
      }
    }
    __builtin_amdgcn_s_setprio(0);
    asm volatile("s_waitcnt vmcnt(0)" ::: "memory");
    __syncthreads();
  }

  #pragma unroll
  for (int i = 0; i < 2; ++i) {
    l_[i] += __shfl_xor(l_[i], 16);
    l_[i] += __shfl_xor(l_[i], 32);
  }
  float linv[2] = {1.f / l_[0], 1.f / l_[1]};
  #pragma unroll
  for (int i = 0; i < 2; ++i) {
    float li[4];
    #pragma unroll
    for (int r = 0; r < 4; ++r) li[r] = __shfl(linv[i], fq * 4 + r);
    #pragma unroll
    for (int r = 0; r < 4; ++r) {
      const long n = qt * 128 + wid * 32 + i * 16 + fq * 4 + r;
      #pragma unroll
      for (int jd = 0; jd < 5; ++jd) {
        const int d = jd * 16 + fr;
        if (d < HD)
          Aproj[((long)b * N_ + n) * C_ + h * HD + d] = f2bf(accO[i][jd][r] * li[r]);
      }
    }
  }
}

extern "C" void kernel_launch(void* const* d_in, const int* in_sizes, int n_in,
                              void* d_out, int out_size, void* d_ws, size_t ws_size,
                              hipStream_t stream) {
  const float* x     = (const float*)d_in[0];
  const float* Wqkv  = (const float*)d_in[1];
  const float* Wproj = (const float*)d_in[2];
  const float* bproj = (const float*)d_in[3];
  float* out = (float*)d_out;

  char* ws = (char*)d_ws;
  short* QKVb = (short*)ws;         size_t off = (size_t)4096 * QSTR * 2;
  short* xb  = (short*)(ws + off);  off += (size_t)4096 * 1152 * 2;
  short* Wt  = (short*)(ws + off);  off += (size_t)QSTR * 1152 * 2;   // zero-padded rows 3456..3583
  short* Wpt = (short*)(ws + off);  off += (size_t)1152 * 1152 * 2;
  short* Qp  = (short*)(ws + off);  off += (size_t)B_ * NH * N_ * HDP * 2;
  short* Kp  = (short*)(ws + off);  off += (size_t)B_ * NH * N_ * HDP * 2;
  short* Vt  = (short*)(ws + off);  off += (size_t)B_ * NH * HDV * N_ * 2;
  short* Ap  = (short*)(ws + off);  off += (size_t)4096 * 1152 * 2;

  cvt_bf16<<<(4096 * 1152 / 4 + 255) / 256, 256, 0, stream>>>(x, xb, 4096 * 1152 / 4);
  transpose_cvt<<<dim3(QSTR / 32, 1152 / 32), dim3(32, 8), 0, stream>>>(Wqkv, Wt, 1152, 3456, QSTR);
  transpose_cvt<<<dim3(1152 / 32, 1152 / 32), dim3(32, 8), 0, stream>>>(Wproj, Wpt, 1152, 1152, 1152);
  gemm_bt256<<<dim3(QSTR / 256, 4096 / 256), 512, 0, stream>>>(
      xb, Wt, QKVb, 4096, QSTR, 1152);
  rope_pack<<<B_ * NH * (N_ / 128), 256, 0, stream>>>(QKVb, Qp, Kp, Vt);
  attn<<<B_ * NH * (N_ / 128), 256, 0, stream>>>(Qp, Kp, Vt, Ap);
  gemm_bt<true, false><<<dim3(1152 / 128, 4096 / 128), 256, 0, stream>>>(
      Ap, Wpt, (void*)out, bproj, 4096, 1152, 1152);
}

// Round 9
// 187.088 us; speedup vs baseline: 1.0940x; 1.0199x over previous
//
#include <hip/hip_runtime.h>
#include <hip/hip_bf16.h>

#define B_   2
#define N_   2048
#define C_   1152
#define NH   16
#define HD   72
#define HDP  96    // padded head dim for QK^T (3 x K=32)
#define HDV  80    // padded head dim for PV (5 x 16)
#define QSTR 3584  // padded QKV row stride (3456 -> 14 x 256)
#define KROW 104   // Ks LDS row stride (96 data + 8 pad shorts) -> 2-way reads
#define VROW 72    // Vs LDS row stride (64 data + 8 pad shorts) -> 2-way reads
#define KVB  64    // keys per attention tile (double-buffered)

typedef __attribute__((ext_vector_type(8))) short bf16x8;
typedef __attribute__((ext_vector_type(4))) float f32x4;

__device__ __forceinline__ short f2bf(float f) {
  union { float fv; unsigned int u; } v; v.fv = f;
  unsigned int r = v.u + 0x7fffu + ((v.u >> 16) & 1u);
  return (short)(r >> 16);
}

__device__ __forceinline__ float bf2f(short s) {
  union { unsigned u; float f; } v; v.u = ((unsigned)(unsigned short)s) << 16;
  return v.f;
}

__device__ __forceinline__ unsigned pack_bf16(float a, float b) {
  union { __hip_bfloat162 h; unsigned u; } c;
  c.h = __float22bfloat162_rn(make_float2(a, b));  // x=low=a, y=high=b
  return c.u;
}

__device__ __forceinline__ void gload_lds16(const short* g, short* l) {
  __builtin_amdgcn_global_load_lds(
      (const __attribute__((address_space(1))) unsigned int*)g,
      (__attribute__((address_space(3))) unsigned int*)l, 16, 0, 0);
}

// ---------------- elementwise f32 -> bf16 (vectorized x4) ----------------
__global__ void cvt_bf16(const float* __restrict__ in, short* __restrict__ out, int n4) {
  int i = blockIdx.x * 256 + threadIdx.x;
  if (i < n4) {
    float4 v = ((const float4*)in)[i];
    short4 s;
    s.x = f2bf(v.x); s.y = f2bf(v.y); s.z = f2bf(v.z); s.w = f2bf(v.w);
    ((short4*)out)[i] = s;
  }
}

// ---------------- transpose + convert: src (R x Cc f32) -> dst (Np x R bf16), zero-pad rows >= Cc ----
__global__ void transpose_cvt(const float* __restrict__ src, short* __restrict__ dst,
                              int R, int Cc, int Np) {
  __shared__ float tile[32][33];
  const int c0 = blockIdx.x * 32, r0 = blockIdx.y * 32;
  const int tx = threadIdx.x, ty = threadIdx.y;  // 32 x 8
  for (int i = ty; i < 32; i += 8)
    tile[i][tx] = (c0 + tx < Cc) ? src[(long)(r0 + i) * Cc + c0 + tx] : 0.f;
  __syncthreads();
  for (int i = ty; i < 32; i += 8)
    dst[(long)(c0 + i) * R + r0 + tx] = f2bf(tile[tx][i]);
}

// ---------------- GEMM 128^2 (m97-structure, counted-vmcnt raw-barrier dbuf) ----------------
template<bool BIAS, bool OBF>
__global__ __launch_bounds__(256, 2) void gemm_bt(
    const short* __restrict__ A, const short* __restrict__ Bt,
    void* __restrict__ Cv, const float* __restrict__ bias,
    int M, int N, int K) {
  __shared__ __align__(16) short As[2][128 * 32];
  __shared__ __align__(16) short Bs[2][128 * 32];
  const int t = threadIdx.x;
  const int lane = t & 63, wid = t >> 6;
  const int fr = lane & 15, fq = lane >> 4;

  int lin = blockIdx.y * gridDim.x + blockIdx.x;
  const int q8 = (int)(gridDim.x * gridDim.y) >> 3;
  lin = (lin & 7) * q8 + (lin >> 3);
  const int bm = lin / (int)gridDim.x;
  const int bn = lin - bm * (int)gridDim.x;

  const int wr = (wid >> 1) * 64, wc = (wid & 1) * 64;

  const int srow = t >> 2;
  const int scol = (t & 3) * 8;
  const short* Ag = A + (long)(bm * 128 + srow) * K + scol;
  const short* Bg = Bt + (long)(bn * 128 + srow) * K + scol;

  f32x4 acc[4][4] = {};

  auto STAGE = [&](int kt, int bufi) {
    gload_lds16(Ag + kt * 32,                &As[bufi][t * 8]);
    gload_lds16(Ag + kt * 32 + (long)64 * K, &As[bufi][2048 + t * 8]);
    gload_lds16(Bg + kt * 32,                &Bs[bufi][t * 8]);
    gload_lds16(Bg + kt * 32 + (long)64 * K, &Bs[bufi][2048 + t * 8]);
  };

  const int NKT = K / 32;
  STAGE(0, 0);

  for (int kt = 0; kt < NKT; ++kt) {
    const int cur = kt & 1;
    if (kt + 1 < NKT) {
      STAGE(kt + 1, cur ^ 1);
      asm volatile("s_waitcnt vmcnt(4)" ::: "memory");  // oldest 4 (this tile) landed
    } else {
      asm volatile("s_waitcnt vmcnt(0)" ::: "memory");
    }
    __builtin_amdgcn_s_barrier();

    bf16x8 af[4], bf[4];
    #pragma unroll
    for (int i = 0; i < 4; ++i)
      af[i] = *(const bf16x8*)(&As[cur][(wr + i * 16 + fr) * 32 + fq * 8]);
    #pragma unroll
    for (int j = 0; j < 4; ++j)
      bf[j] = *(const bf16x8*)(&Bs[cur][(wc + j * 16 + fr) * 32 + fq * 8]);
    __builtin_amdgcn_s_setprio(1);
    #pragma unroll
    for (int i = 0; i < 4; ++i)
      #pragma unroll
      for (int j = 0; j < 4; ++j)
        acc[i][j] = __builtin_amdgcn_mfma_f32_16x16x32_bf16(af[i], bf[j], acc[i][j], 0, 0, 0);
    __builtin_amdgcn_s_setprio(0);
    __builtin_amdgcn_s_barrier();  // reads of cur done before next STAGE overwrites it
  }

  #pragma unroll
  for (int i = 0; i < 4; ++i) {
    #pragma unroll
    for (int j = 0; j < 4; ++j) {
      const long row0 = (long)bm * 128 + wr + i * 16 + fq * 4;
      const int col = bn * 128 + wc + j * 16 + fr;
      const float bv = BIAS ? bias[col] : 0.f;
      #pragma unroll
      for (int r = 0; r < 4; ++r) {
        const float val = acc[i][j][r] + bv;
        if constexpr (OBF)
          ((short*)Cv)[(row0 + r) * (long)N + col] = f2bf(val);
        else
          ((float*)Cv)[(row0 + r) * (long)N + col] = val;
      }
    }
  }
}

// ---------------- GEMM 256^2, BK=64, 8 waves, ONE barrier per K-tile ----------------
// Hazard analysis: a wave reaching the boundary barrier has already retired its
// ds_reads (lgkm waits precede its MFMAs, which precede the barrier), so staging
// into the freed buffer right after ONE boundary barrier is race-free. Inner
// tile = vmcnt(0) + s_barrier + {stage 8 loads early} || {24 ds_read} || {64
// MFMA} with NO intra-tile barriers -> 64 MFMA per barrier (vs 16 in r8).
// LDS chunk-XOR swizzle phys = lc ^ (row&7) on global source + read addr.
__global__ __launch_bounds__(512, 2) void gemm_bt256(
    const short* __restrict__ A, const short* __restrict__ Bt,
    short* __restrict__ Cv, int M, int N, int K) {
  __shared__ __align__(16) short As[2][256 * 64];  // 2 x 32 KB
  __shared__ __align__(16) short Bs[2][256 * 64];  // 2 x 32 KB
  const int t = threadIdx.x;
  const int lane = t & 63, wid = t >> 6;
  const int fr = lane & 15, fq = lane >> 4;
  const int wm = wid >> 2, wn = wid & 3;   // 2M x 4N wave grid
  const int rx = fr & 7;                   // read-side chunk XOR (= row&7 of frag rows)

  int lin = blockIdx.y * gridDim.x + blockIdx.x;
  const int q8 = (int)(gridDim.x * gridDim.y) >> 3;
  lin = (lin & 7) * q8 + (lin >> 3);
  const int bm = lin / (int)gridDim.x;
  const int bn = lin - bm * (int)gridDim.x;

  // staging source offsets: 4 rounds/matrix/K-tile; chunk p = r*512+t
  // row = p>>3, phys chunk = p&7, logical = phys ^ (row&7)
  int soff[4];
  #pragma unroll
  for (int r = 0; r < 4; ++r) {
    const int p = r * 512 + t;
    const int row = p >> 3, pc = p & 7;
    soff[r] = row * K + (pc ^ (row & 7)) * 8;
  }
  const short* Ag = A + (long)bm * 256 * K;
  const short* Bg = Bt + (long)bn * 256 * K;

  f32x4 acc[8][4] = {};

  const int NKT = K / 64;
  // prologue: stage tile 0 into buf 0
  #pragma unroll
  for (int r = 0; r < 4; ++r)
    gload_lds16(Ag + soff[r], &As[0][(r * 512 + t) * 8]);
  #pragma unroll
  for (int r = 0; r < 4; ++r)
    gload_lds16(Bg + soff[r], &Bs[0][(r * 512 + t) * 8]);

  for (int kt = 0; kt < NKT; ++kt) {
    const int cur = kt & 1;
    const bool pre = (kt + 1 < NKT);
    asm volatile("s_waitcnt vmcnt(0)" ::: "memory");  // this tile's 8 loads landed
    __builtin_amdgcn_s_barrier();                     // everyone's loads visible; prev bufs free
    const short* Ac = &As[cur][0];
    const short* Bc = &Bs[cur][0];
    bf16x8 af[4][2], bf0[2][2], bf1[2][2];

    // ---- phase 0: stage A(kt+1); read af(m-half0)+bf0; MFMA (m0,n0) ----
    if (pre) {
      #pragma unroll
      for (int r = 0; r < 4; ++r)
        gload_lds16(Ag + soff[r] + (kt + 1) * 64, &As[cur ^ 1][(r * 512 + t) * 8]);
    }
    #pragma unroll
    for (int i = 0; i < 4; ++i)
      #pragma unroll
      for (int kk = 0; kk < 2; ++kk)
        af[i][kk] = *(const bf16x8*)(Ac + (wm * 128 + i * 16 + fr) * 64 + (((kk * 4 + fq) ^ rx) * 8));
    #pragma unroll
    for (int j = 0; j < 2; ++j)
      #pragma unroll
      for (int kk = 0; kk < 2; ++kk)
        bf0[j][kk] = *(const bf16x8*)(Bc + (wn * 64 + j * 16 + fr) * 64 + (((kk * 4 + fq) ^ rx) * 8));
    __builtin_amdgcn_s_setprio(1);
    #pragma unroll
    for (int i = 0; i < 4; ++i)
      #pragma unroll
      for (int j = 0; j < 2; ++j)
        #pragma unroll
        for (int kk = 0; kk < 2; ++kk)
          acc[i][j] = __builtin_amdgcn_mfma_f32_16x16x32_bf16(af[i][kk], bf0[j][kk], acc[i][j], 0, 0, 0);
    __builtin_amdgcn_s_setprio(0);

    // ---- phase 1: stage B(kt+1); read bf1; MFMA (m0,n1) ----
    if (pre) {
      #pragma unroll
      for (int r = 0; r < 4; ++r)
        gload_lds16(Bg + soff[r] + (kt + 1) * 64, &Bs[cur ^ 1][(r * 512 + t) * 8]);
    }
    #pragma unroll
    for (int j = 0; j < 2; ++j)
      #pragma unroll
      for (int kk = 0; kk < 2; ++kk)
        bf1[j][kk] = *(const bf16x8*)(Bc + (wn * 64 + 32 + j * 16 + fr) * 64 + (((kk * 4 + fq) ^ rx) * 8));
    __builtin_amdgcn_s_setprio(1);
    #pragma unroll
    for (int i = 0; i < 4; ++i)
      #pragma unroll
      for (int j = 0; j < 2; ++j)
        #pragma unroll
        for (int kk = 0; kk < 2; ++kk)
          acc[i][2 + j] = __builtin_amdgcn_mfma_f32_16x16x32_bf16(af[i][kk], bf1[j][kk], acc[i][2 + j], 0, 0, 0);
    __builtin_amdgcn_s_setprio(0);

    // ---- phase 2: read af(m-half1); MFMA (m1,n0) ----
    #pragma unroll
    for (int i = 0; i < 4; ++i)
      #pragma unroll
      for (int kk = 0; kk < 2; ++kk)
        af[i][kk] = *(const bf16x8*)(Ac + (wm * 128 + 64 + i * 16 + fr) * 64 + (((kk * 4 + fq) ^ rx) * 8));
    __builtin_amdgcn_s_setprio(1);
    #pragma unroll
    for (int i = 0; i < 4; ++i)
      #pragma unroll
      for (int j = 0; j < 2; ++j)
        #pragma unroll
        for (int kk = 0; kk < 2; ++kk)
          acc[4 + i][j] = __builtin_amdgcn_mfma_f32_16x16x32_bf16(af[i][kk], bf0[j][kk], acc[4 + i][j], 0, 0, 0);
    __builtin_amdgcn_s_setprio(0);

    // ---- phase 3: MFMA (m1,n1) ----
    __builtin_amdgcn_s_setprio(1);
    #pragma unroll
    for (int i = 0; i < 4; ++i)
      #pragma unroll
      for (int j = 0; j < 2; ++j)
        #pragma unroll
        for (int kk = 0; kk < 2; ++kk)
          acc[4 + i][2 + j] = __builtin_amdgcn_mfma_f32_16x16x32_bf16(af[i][kk], bf1[j][kk], acc[4 + i][2 + j], 0, 0, 0);
    __builtin_amdgcn_s_setprio(0);
  }

  #pragma unroll
  for (int mi = 0; mi < 8; ++mi) {
    #pragma unroll
    for (int j = 0; j < 4; ++j) {
      const long row0 = (long)bm * 256 + wm * 128 + (mi >> 2) * 64 + (mi & 3) * 16 + fq * 4;
      const int col = bn * 256 + wn * 64 + j * 16 + fr;
      #pragma unroll
      for (int r = 0; r < 4; ++r)
        Cv[(row0 + r) * (long)N + col] = f2bf(acc[mi][j][r]);
    }
  }
}

// ---------------- RoPE + repack (bf16 QKV input, stride QSTR) ----------------
__global__ __launch_bounds__(256) void rope_pack(
    const short* __restrict__ QKV, short* __restrict__ Qp,
    short* __restrict__ Kp, short* __restrict__ Vt) {
  const int blk = blockIdx.x;
  const int nt = blk & 15;
  const int h = (blk >> 4) & 15;
  const int b = blk >> 8;
  const int t = threadIdx.x;
  const int n0 = nt * 128;
  const float qscale = 0.17002324f;  // (1/sqrt(72)) * log2(e)
  const float PI = 3.14159265358979323846f;

  for (int which = 0; which < 2; ++which) {
    short* dst = which ? Kp : Qp;
    const float sc = which ? 1.0f : qscale;
    for (int idx = t; idx < 128 * 48; idx += 256) {
      const int r = idx / 48;
      const int p = idx - r * 48;   // pair index: d = 2p, 2p+1
      const int n = n0 + r;
      float vx = 0.f, vy = 0.f;
      if (p < 36) {
        short2 v2 = *(const short2*)(QKV + ((long)(b * N_ + n)) * QSTR + which * C_ + h * HD + 2 * p);
        vx = bf2f(v2.x); vy = bf2f(v2.y);
      }
      float o0 = vx, o1 = vy;
      if (p < 24) {
        float pos;
        if (p < 8)       pos = -1.f + (2.f / 7.f)  * (float)(n >> 8);
        else if (p < 16) pos = -1.f + (2.f / 15.f) * (float)((n >> 4) & 15);
        else             pos = -1.f + (2.f / 15.f) * (float)(n & 15);
        const float base = (1.f + (127.f / 7.f) * (float)(p & 7)) * PI;
        const float f = pos * base;
        const float cs = cosf(f), sn = sinf(f);
        o0 = vx * cs - vy * sn;
        o1 = vy * cs + vx * sn;
      }
      short2 ov; ov.x = f2bf(o0 * sc); ov.y = f2bf(o1 * sc);
      *(short2*)(dst + (((long)(b * NH + h)) * N_ + n) * HDP + 2 * p) = ov;
    }
  }

  __shared__ short vt[128][82];
  for (int idx = t; idx < 128 * 40; idx += 256) {
    const int r = idx / 40, p = idx - r * 40;
    short2 v2; v2.x = 0; v2.y = 0;
    if (p < 36)
      v2 = *(const short2*)(QKV + ((long)(b * N_ + n0 + r)) * QSTR + 2 * C_ + h * HD + 2 * p);
    *(short2*)(&vt[r][2 * p]) = v2;
  }
  __syncthreads();
  for (int idx = t; idx < HDV * 128; idx += 256) {
    const int d = idx >> 7, nn = idx & 127;
    const int c = nn & 31;
    const int nsrc = (nn & 96) | (((c >> 2) & 1) * 16 + ((c >> 3) & 3) * 4 + (c & 3));
    Vt[(((long)(b * NH + h)) * HDV + d) * N_ + n0 + nn] = vt[nsrc][d];
  }
}

// ---------------- flash attention (round-6 structure: 32 q/wave, 512 blocks) ----------------
__global__ __launch_bounds__(256, 3) void attn(
    const short* __restrict__ Qp, const short* __restrict__ Kp,
    const short* __restrict__ Vt, short* __restrict__ Aproj) {
  __shared__ __align__(16) short Ks[2][KVB * KROW];  // 2 x 13 KB
  __shared__ __align__(16) short Vs[2][HDV * VROW];  // 2 x 11.25 KB
  int blk = blockIdx.x;
  blk = (blk & 7) * 64 + (blk >> 3);   // 512 % 8 == 0 -> bijective
  const int qt = blk & 15;
  const int h = (blk >> 4) & 15;
  const int b = blk >> 8;
  const int t = threadIdx.x, lane = t & 63, wid = t >> 6;
  const int fr = lane & 15, fq = lane >> 4;

  const long bh = (long)(b * NH + h);
  const short* Qg = Qp + (bh * N_ + qt * 128) * HDP;
  const short* Kg = Kp + bh * N_ * HDP;
  const short* Vg = Vt + bh * HDV * N_;

  int koff[4];
  #pragma unroll
  for (int it = 0; it < 4; ++it) {
    const int p = it * 256 + t;
    const int row = p / 13, c = p - row * 13;
    koff[it] = row * HDP + (c < 12 ? c * 8 : 0);
  }
  int voff[3];
  #pragma unroll
  for (int it = 0; it < 3; ++it) {
    const int p = it * 256 + t;
    const int row = p / 9, c = p - row * 9;
    voff[it] = row * N_ + (c < 8 ? c * 8 : 0);
  }

  bf16x8 qf[2][3];
  #pragma unroll
  for (int i = 0; i < 2; ++i)
    #pragma unroll
    for (int kk = 0; kk < 3; ++kk)
      qf[i][kk] = *(const bf16x8*)(Qg + (wid * 32 + i * 16 + fr) * HDP + kk * 32 + fq * 8);

  f32x4 accO[2][5] = {};
  float l_[2] = {0.f, 0.f};

  auto STAGE = [&](int kt, int bufi) {
    const short* Ksrc = Kg + (long)kt * KVB * HDP;
    const short* Vsrc = Vg + kt * KVB;
    short* KD = &Ks[bufi][0];
    short* VD = &Vs[bufi][0];
    #pragma unroll
    for (int it = 0; it < 4; ++it)
      if (it < 3 || t < 64)
        gload_lds16(Ksrc + koff[it], KD + (it * 256 + t) * 8);
    #pragma unroll
    for (int it = 0; it < 3; ++it)
      if (it < 2 || t < 208)
        gload_lds16(Vsrc + voff[it], VD + (it * 256 + t) * 8);
  };

  STAGE(0, 0);
  asm volatile("s_waitcnt vmcnt(0)" ::: "memory");
  __syncthreads();

  for (int kt = 0; kt < 32; ++kt) {
    const int cur = kt & 1;
    if (kt < 31) STAGE(kt + 1, cur ^ 1);
    const short* KsC = &Ks[cur][0];
    const short* VsC = &Vs[cur][0];

    f32x4 s[2][4] = {};
    __builtin_amdgcn_s_setprio(1);
    #pragma unroll
    for (int j = 0; j < 4; ++j) {
      #pragma unroll
      for (int kk = 0; kk < 3; ++kk) {
        bf16x8 kf = *(const bf16x8*)(KsC + (j * 16 + fr) * KROW + (kk * 4 + fq) * 8);
        s[0][j] = __builtin_amdgcn_mfma_f32_16x16x32_bf16(kf, qf[0][kk], s[0][j], 0, 0, 0);
        s[1][j] = __builtin_amdgcn_mfma_f32_16x16x32_bf16(kf, qf[1][kk], s[1][j], 0, 0, 0);
      }
    }
    __builtin_amdgcn_s_setprio(0);

    #pragma unroll
    for (int i = 0; i < 2; ++i) {
      float psum = 0.f;
      #pragma unroll
      for (int j = 0; j < 4; ++j)
        #pragma unroll
        for (int r = 0; r < 4; ++r) {
          const float p = __builtin_amdgcn_exp2f(s[i][j][r]);
          s[i][j][r] = p;
          psum += p;
        }
      l_[i] += psum;
    }

    __builtin_amdgcn_s_setprio(1);
    #pragma unroll
    for (int g = 0; g < 2; ++g) {
      union { unsigned u[4]; bf16x8 v; } pf0, pf1;
      pf0.u[0] = pack_bf16(s[0][2 * g][0],     s[0][2 * g][1]);
      pf0.u[1] = pack_bf16(s[0][2 * g][2],     s[0][2 * g][3]);
      pf0.u[2] = pack_bf16(s[0][2 * g + 1][0], s[0][2 * g + 1][1]);
      pf0.u[3] = pack_bf16(s[0][2 * g + 1][2], s[0][2 * g + 1][3]);
      pf1.u[0] = pack_bf16(s[1][2 * g][0],     s[1][2 * g][1]);
      pf1.u[1] = pack_bf16(s[1][2 * g][2],     s[1][2 * g][3]);
      pf1.u[2] = pack_bf16(s[1][2 * g + 1][0], s[1][2 * g + 1][1]);
      pf1.u[3] = pack_bf16(s[1][2 * g + 1][2], s[1][2 * g + 1][3]);
      #pragma unroll
      for (int jd = 0; jd < 5; ++jd) {
        bf16x8 vf = *(const bf16x8*)(VsC + (jd * 16 + fr) * VROW + (g * 4 + fq) * 8);
        accO[0][jd] = __builtin_amdgcn_mfma_f32_16x16x32_bf16(pf0.v, vf, accO[0][jd], 0, 0, 0);
        accO[1][jd] = __builtin_amdgcn_mfma_f32_16x16x32_bf16(pf1.v, vf, accO[1][jd], 0, 0, 0);
      }
    }
    __builtin_amdgcn_s_setprio(0);
    asm volatile("s_waitcnt vmcnt(0)" ::: "memory");
    __syncthreads();
  }

  #pragma unroll
  for (int i = 0; i < 2; ++i) {
    l_[i] += __shfl_xor(l_[i], 16);
    l_[i] += __shfl_xor(l_[i], 32);
  }
  float linv[2] = {1.f / l_[0], 1.f / l_[1]};
  #pragma unroll
  for (int i = 0; i < 2; ++i) {
    float li[4];
    #pragma unroll
    for (int r = 0; r < 4; ++r) li[r] = __shfl(linv[i], fq * 4 + r);
    #pragma unroll
    for (int r = 0; r < 4; ++r) {
      const long n = qt * 128 + wid * 32 + i * 16 + fq * 4 + r;
      #pragma unroll
      for (int jd = 0; jd < 5; ++jd) {
        const int d = jd * 16 + fr;
        if (d < HD)
          Aproj[((long)b * N_ + n) * C_ + h * HD + d] = f2bf(accO[i][jd][r] * li[r]);
      }
    }
  }
}

extern "C" void kernel_launch(void* const* d_in, const int* in_sizes, int n_in,
                              void* d_out, int out_size, void* d_ws, size_t ws_size,
                              hipStream_t stream) {
  const float* x     = (const float*)d_in[0];
  const float* Wqkv  = (const float*)d_in[1];
  const float* Wproj = (const float*)d_in[2];
  const float* bproj = (const float*)d_in[3];
  float* out = (float*)d_out;

  char* ws = (char*)d_ws;
  short* QKVb = (short*)ws;         size_t off = (size_t)4096 * QSTR * 2;
  short* xb  = (short*)(ws + off);  off += (size_t)4096 * 1152 * 2;
  short* Wt  = (short*)(ws + off);  off += (size_t)QSTR * 1152 * 2;   // zero-padded rows 3456..3583
  short* Wpt = (short*)(ws + off);  off += (size_t)1152 * 1152 * 2;
  short* Qp  = (short*)(ws + off);  off += (size_t)B_ * NH * N_ * HDP * 2;
  short* Kp  = (short*)(ws + off);  off += (size_t)B_ * NH * N_ * HDP * 2;
  short* Vt  = (short*)(ws + off);  off += (size_t)B_ * NH * HDV * N_ * 2;
  short* Ap  = (short*)(ws + off);  off += (size_t)4096 * 1152 * 2;

  cvt_bf16<<<(4096 * 1152 / 4 + 255) / 256, 256, 0, stream>>>(x, xb, 4096 * 1152 / 4);
  transpose_cvt<<<dim3(QSTR / 32, 1152 / 32), dim3(32, 8), 0, stream>>>(Wqkv, Wt, 1152, 3456, QSTR);
  transpose_cvt<<<dim3(1152 / 32, 1152 / 32), dim3(32, 8), 0, stream>>>(Wproj, Wpt, 1152, 1152, 1152);
  gemm_bt256<<<dim3(QSTR / 256, 4096 / 256), 512, 0, stream>>>(
      xb, Wt, QKVb, 4096, QSTR, 1152);
  rope_pack<<<B_ * NH * (N_ / 128), 256, 0, stream>>>(QKVb, Qp, Kp, Vt);
  attn<<<B_ * NH * (N_ / 128), 256, 0, stream>>>(Qp, Kp, Vt, Ap);
  gemm_bt<true, false><<<dim3(1152 / 128, 4096 / 128), 256, 0, stream>>>(
      Ap, Wpt, (void*)out, bproj, 4096, 1152, 1152);
}

// Round 10
// 179.146 us; speedup vs baseline: 1.1426x; 1.0443x over previous
//
#include <hip/hip_runtime.h>
#include <hip/hip_bf16.h>

#define B_   2
#define N_   2048
#define C_   1152
#define NH   16
#define HD   72
#define HDP  96    // padded head dim for QK^T (3 x K=32)
#define HDV  80    // padded head dim for PV (5 x 16)
#define QSTR 3584  // padded QKV row stride (3456 -> 14 x 256)
#define KROW 104   // Ks LDS row stride (96 data + 8 pad shorts) -> 2-way reads
#define VROW 72    // Vs LDS row stride (64 data + 8 pad shorts) -> 2-way reads
#define KVB  64    // keys per attention tile (triple-buffered)
#define KCH  832   // K chunks (64 rows x 13)
#define VCH  720   // V chunks (80 rows x 9)
#define TCH  1552  // total chunks per tile
#define WCH  388   // chunks per wave (1552/4)

typedef __attribute__((ext_vector_type(8))) short bf16x8;
typedef __attribute__((ext_vector_type(4))) float f32x4;

__device__ __forceinline__ short f2bf(float f) {
  union { float fv; unsigned int u; } v; v.fv = f;
  unsigned int r = v.u + 0x7fffu + ((v.u >> 16) & 1u);
  return (short)(r >> 16);
}

__device__ __forceinline__ float bf2f(short s) {
  union { unsigned u; float f; } v; v.u = ((unsigned)(unsigned short)s) << 16;
  return v.f;
}

__device__ __forceinline__ unsigned pack_bf16(float a, float b) {
  union { __hip_bfloat162 h; unsigned u; } c;
  c.h = __float22bfloat162_rn(make_float2(a, b));  // x=low=a, y=high=b
  return c.u;
}

__device__ __forceinline__ void gload_lds16(const short* g, short* l) {
  __builtin_amdgcn_global_load_lds(
      (const __attribute__((address_space(1))) unsigned int*)g,
      (__attribute__((address_space(3))) unsigned int*)l, 16, 0, 0);
}

// ---------------- fused prep: x->bf16, Wqkv^T (pad to QSTR), Wproj^T ----------------
__global__ __launch_bounds__(256) void prep(
    const float* __restrict__ x, short* __restrict__ xb,
    const float* __restrict__ Wqkv, short* __restrict__ Wt,
    const float* __restrict__ Wproj, short* __restrict__ Wpt) {
  int bid = blockIdx.x;
  if (bid < 4608) {  // cvt x: 4096*1152/4 float4s, exact
    const int i = bid * 256 + threadIdx.x;
    float4 v = ((const float4*)x)[i];
    short4 s;
    s.x = f2bf(v.x); s.y = f2bf(v.y); s.z = f2bf(v.z); s.w = f2bf(v.w);
    ((short4*)xb)[i] = s;
    return;
  }
  bid -= 4608;
  const float* src; short* dst; int Cc, bx, by;
  if (bid < 4032) {       // Wqkv: grid 112 x 36
    bx = bid % 112; by = bid / 112; src = Wqkv; dst = Wt; Cc = 3456;
  } else {                // Wproj: grid 36 x 36
    bid -= 4032;
    bx = bid % 36; by = bid / 36; src = Wproj; dst = Wpt; Cc = 1152;
  }
  __shared__ float tile[32][33];
  const int c0 = bx * 32, r0 = by * 32;
  const int tx = threadIdx.x & 31, ty = threadIdx.x >> 5;
  for (int i = ty; i < 32; i += 8)
    tile[i][tx] = (c0 + tx < Cc) ? src[(long)(r0 + i) * Cc + c0 + tx] : 0.f;
  __syncthreads();
  for (int i = ty; i < 32; i += 8)
    dst[(long)(c0 + i) * 1152 + r0 + tx] = f2bf(tile[tx][i]);
}

// ---------------- GEMM 128^2 (counted-vmcnt raw-barrier dbuf) ----------------
template<bool BIAS, bool OBF>
__global__ __launch_bounds__(256, 2) void gemm_bt(
    const short* __restrict__ A, const short* __restrict__ Bt,
    void* __restrict__ Cv, const float* __restrict__ bias,
    int M, int N, int K) {
  __shared__ __align__(16) short As[2][128 * 32];
  __shared__ __align__(16) short Bs[2][128 * 32];
  const int t = threadIdx.x;
  const int lane = t & 63, wid = t >> 6;
  const int fr = lane & 15, fq = lane >> 4;

  int lin = blockIdx.y * gridDim.x + blockIdx.x;
  const int q8 = (int)(gridDim.x * gridDim.y) >> 3;
  lin = (lin & 7) * q8 + (lin >> 3);
  const int bm = lin / (int)gridDim.x;
  const int bn = lin - bm * (int)gridDim.x;

  const int wr = (wid >> 1) * 64, wc = (wid & 1) * 64;

  const int srow = t >> 2;
  const int scol = (t & 3) * 8;
  const short* Ag = A + (long)(bm * 128 + srow) * K + scol;
  const short* Bg = Bt + (long)(bn * 128 + srow) * K + scol;

  f32x4 acc[4][4] = {};

  auto STAGE = [&](int kt, int bufi) {
    gload_lds16(Ag + kt * 32,                &As[bufi][t * 8]);
    gload_lds16(Ag + kt * 32 + (long)64 * K, &As[bufi][2048 + t * 8]);
    gload_lds16(Bg + kt * 32,                &Bs[bufi][t * 8]);
    gload_lds16(Bg + kt * 32 + (long)64 * K, &Bs[bufi][2048 + t * 8]);
  };

  const int NKT = K / 32;
  STAGE(0, 0);

  for (int kt = 0; kt < NKT; ++kt) {
    const int cur = kt & 1;
    if (kt + 1 < NKT) {
      STAGE(kt + 1, cur ^ 1);
      asm volatile("s_waitcnt vmcnt(4)" ::: "memory");
    } else {
      asm volatile("s_waitcnt vmcnt(0)" ::: "memory");
    }
    __builtin_amdgcn_s_barrier();

    bf16x8 af[4], bf[4];
    #pragma unroll
    for (int i = 0; i < 4; ++i)
      af[i] = *(const bf16x8*)(&As[cur][(wr + i * 16 + fr) * 32 + fq * 8]);
    #pragma unroll
    for (int j = 0; j < 4; ++j)
      bf[j] = *(const bf16x8*)(&Bs[cur][(wc + j * 16 + fr) * 32 + fq * 8]);
    __builtin_amdgcn_s_setprio(1);
    #pragma unroll
    for (int i = 0; i < 4; ++i)
      #pragma unroll
      for (int j = 0; j < 4; ++j)
        acc[i][j] = __builtin_amdgcn_mfma_f32_16x16x32_bf16(af[i], bf[j], acc[i][j], 0, 0, 0);
    __builtin_amdgcn_s_setprio(0);
    __builtin_amdgcn_s_barrier();
  }

  #pragma unroll
  for (int i = 0; i < 4; ++i) {
    #pragma unroll
    for (int j = 0; j < 4; ++j) {
      const long row0 = (long)bm * 128 + wr + i * 16 + fq * 4;
      const int col = bn * 128 + wc + j * 16 + fr;
      const float bv = BIAS ? bias[col] : 0.f;
      #pragma unroll
      for (int r = 0; r < 4; ++r) {
        const float val = acc[i][j][r] + bv;
        if constexpr (OBF)
          ((short*)Cv)[(row0 + r) * (long)N + col] = f2bf(val);
        else
          ((float*)Cv)[(row0 + r) * (long)N + col] = val;
      }
    }
  }
}

// ---------------- GEMM 256^2, BK=64, 8 waves, ONE barrier per K-tile ----------------
__global__ __launch_bounds__(512, 2) void gemm_bt256(
    const short* __restrict__ A, const short* __restrict__ Bt,
    short* __restrict__ Cv, int M, int N, int K) {
  __shared__ __align__(16) short As[2][256 * 64];
  __shared__ __align__(16) short Bs[2][256 * 64];
  const int t = threadIdx.x;
  const int lane = t & 63, wid = t >> 6;
  const int fr = lane & 15, fq = lane >> 4;
  const int wm = wid >> 2, wn = wid & 3;
  const int rx = fr & 7;

  int lin = blockIdx.y * gridDim.x + blockIdx.x;
  const int q8 = (int)(gridDim.x * gridDim.y) >> 3;
  lin = (lin & 7) * q8 + (lin >> 3);
  const int bm = lin / (int)gridDim.x;
  const int bn = lin - bm * (int)gridDim.x;

  int soff[4];
  #pragma unroll
  for (int r = 0; r < 4; ++r) {
    const int p = r * 512 + t;
    const int row = p >> 3, pc = p & 7;
    soff[r] = row * K + (pc ^ (row & 7)) * 8;
  }
  const short* Ag = A + (long)bm * 256 * K;
  const short* Bg = Bt + (long)bn * 256 * K;

  f32x4 acc[8][4] = {};

  const int NKT = K / 64;
  #pragma unroll
  for (int r = 0; r < 4; ++r)
    gload_lds16(Ag + soff[r], &As[0][(r * 512 + t) * 8]);
  #pragma unroll
  for (int r = 0; r < 4; ++r)
    gload_lds16(Bg + soff[r], &Bs[0][(r * 512 + t) * 8]);

  for (int kt = 0; kt < NKT; ++kt) {
    const int cur = kt & 1;
    const bool pre = (kt + 1 < NKT);
    asm volatile("s_waitcnt vmcnt(0)" ::: "memory");
    __builtin_amdgcn_s_barrier();
    const short* Ac = &As[cur][0];
    const short* Bc = &Bs[cur][0];
    bf16x8 af[4][2], bf0[2][2], bf1[2][2];

    if (pre) {
      #pragma unroll
      for (int r = 0; r < 4; ++r)
        gload_lds16(Ag + soff[r] + (kt + 1) * 64, &As[cur ^ 1][(r * 512 + t) * 8]);
    }
    #pragma unroll
    for (int i = 0; i < 4; ++i)
      #pragma unroll
      for (int kk = 0; kk < 2; ++kk)
        af[i][kk] = *(const bf16x8*)(Ac + (wm * 128 + i * 16 + fr) * 64 + (((kk * 4 + fq) ^ rx) * 8));
    #pragma unroll
    for (int j = 0; j < 2; ++j)
      #pragma unroll
      for (int kk = 0; kk < 2; ++kk)
        bf0[j][kk] = *(const bf16x8*)(Bc + (wn * 64 + j * 16 + fr) * 64 + (((kk * 4 + fq) ^ rx) * 8));
    __builtin_amdgcn_s_setprio(1);
    #pragma unroll
    for (int i = 0; i < 4; ++i)
      #pragma unroll
      for (int j = 0; j < 2; ++j)
        #pragma unroll
        for (int kk = 0; kk < 2; ++kk)
          acc[i][j] = __builtin_amdgcn_mfma_f32_16x16x32_bf16(af[i][kk], bf0[j][kk], acc[i][j], 0, 0, 0);
    __builtin_amdgcn_s_setprio(0);

    if (pre) {
      #pragma unroll
      for (int r = 0; r < 4; ++r)
        gload_lds16(Bg + soff[r] + (kt + 1) * 64, &Bs[cur ^ 1][(r * 512 + t) * 8]);
    }
    #pragma unroll
    for (int j = 0; j < 2; ++j)
      #pragma unroll
      for (int kk = 0; kk < 2; ++kk)
        bf1[j][kk] = *(const bf16x8*)(Bc + (wn * 64 + 32 + j * 16 + fr) * 64 + (((kk * 4 + fq) ^ rx) * 8));
    __builtin_amdgcn_s_setprio(1);
    #pragma unroll
    for (int i = 0; i < 4; ++i)
      #pragma unroll
      for (int j = 0; j < 2; ++j)
        #pragma unroll
        for (int kk = 0; kk < 2; ++kk)
          acc[i][2 + j] = __builtin_amdgcn_mfma_f32_16x16x32_bf16(af[i][kk], bf1[j][kk], acc[i][2 + j], 0, 0, 0);
    __builtin_amdgcn_s_setprio(0);

    #pragma unroll
    for (int i = 0; i < 4; ++i)
      #pragma unroll
      for (int kk = 0; kk < 2; ++kk)
        af[i][kk] = *(const bf16x8*)(Ac + (wm * 128 + 64 + i * 16 + fr) * 64 + (((kk * 4 + fq) ^ rx) * 8));
    __builtin_amdgcn_s_setprio(1);
    #pragma unroll
    for (int i = 0; i < 4; ++i)
      #pragma unroll
      for (int j = 0; j < 2; ++j)
        #pragma unroll
        for (int kk = 0; kk < 2; ++kk)
          acc[4 + i][j] = __builtin_amdgcn_mfma_f32_16x16x32_bf16(af[i][kk], bf0[j][kk], acc[4 + i][j], 0, 0, 0);
    __builtin_amdgcn_s_setprio(0);

    __builtin_amdgcn_s_setprio(1);
    #pragma unroll
    for (int i = 0; i < 4; ++i)
      #pragma unroll
      for (int j = 0; j < 2; ++j)
        #pragma unroll
        for (int kk = 0; kk < 2; ++kk)
          acc[4 + i][2 + j] = __builtin_amdgcn_mfma_f32_16x16x32_bf16(af[i][kk], bf1[j][kk], acc[4 + i][2 + j], 0, 0, 0);
    __builtin_amdgcn_s_setprio(0);
  }

  #pragma unroll
  for (int mi = 0; mi < 8; ++mi) {
    #pragma unroll
    for (int j = 0; j < 4; ++j) {
      const long row0 = (long)bm * 256 + wm * 128 + (mi >> 2) * 64 + (mi & 3) * 16 + fq * 4;
      const int col = bn * 256 + wn * 64 + j * 16 + fr;
      #pragma unroll
      for (int r = 0; r < 4; ++r)
        Cv[(row0 + r) * (long)N + col] = f2bf(acc[mi][j][r]);
    }
  }
}

// ---------------- RoPE + repack (bf16 QKV input, stride QSTR) ----------------
__global__ __launch_bounds__(256) void rope_pack(
    const short* __restrict__ QKV, short* __restrict__ Qp,
    short* __restrict__ Kp, short* __restrict__ Vt) {
  const int blk = blockIdx.x;
  const int nt = blk & 15;
  const int h = (blk >> 4) & 15;
  const int b = blk >> 8;
  const int t = threadIdx.x;
  const int n0 = nt * 128;
  const float qscale = 0.17002324f;  // (1/sqrt(72)) * log2(e)
  const float PI = 3.14159265358979323846f;

  for (int which = 0; which < 2; ++which) {
    short* dst = which ? Kp : Qp;
    const float sc = which ? 1.0f : qscale;
    for (int idx = t; idx < 128 * 48; idx += 256) {
      const int r = idx / 48;
      const int p = idx - r * 48;
      const int n = n0 + r;
      float vx = 0.f, vy = 0.f;
      if (p < 36) {
        short2 v2 = *(const short2*)(QKV + ((long)(b * N_ + n)) * QSTR + which * C_ + h * HD + 2 * p);
        vx = bf2f(v2.x); vy = bf2f(v2.y);
      }
      float o0 = vx, o1 = vy;
      if (p < 24) {
        float pos;
        if (p < 8)       pos = -1.f + (2.f / 7.f)  * (float)(n >> 8);
        else if (p < 16) pos = -1.f + (2.f / 15.f) * (float)((n >> 4) & 15);
        else             pos = -1.f + (2.f / 15.f) * (float)(n & 15);
        const float base = (1.f + (127.f / 7.f) * (float)(p & 7)) * PI;
        const float f = pos * base;
        const float cs = cosf(f), sn = sinf(f);
        o0 = vx * cs - vy * sn;
        o1 = vy * cs + vx * sn;
      }
      short2 ov; ov.x = f2bf(o0 * sc); ov.y = f2bf(o1 * sc);
      *(short2*)(dst + (((long)(b * NH + h)) * N_ + n) * HDP + 2 * p) = ov;
    }
  }

  __shared__ short vt[128][82];
  for (int idx = t; idx < 128 * 40; idx += 256) {
    const int r = idx / 40, p = idx - r * 40;
    short2 v2; v2.x = 0; v2.y = 0;
    if (p < 36)
      v2 = *(const short2*)(QKV + ((long)(b * N_ + n0 + r)) * QSTR + 2 * C_ + h * HD + 2 * p);
    *(short2*)(&vt[r][2 * p]) = v2;
  }
  __syncthreads();
  for (int idx = t; idx < HDV * 128; idx += 256) {
    const int d = idx >> 7, nn = idx & 127;
    const int c = nn & 31;
    const int nsrc = (nn & 96) | (((c >> 2) & 1) * 16 + ((c >> 3) & 3) * 4 + (c & 3));
    Vt[(((long)(b * NH + h)) * HDV + d) * N_ + n0 + nn] = vt[nsrc][d];
  }
}

// ---------------- flash attention: triple-buffered KV, counted vmcnt(7) ----------------
// K+V fused into one 1552-chunk LDS region x 3 buffers. Every wave issues
// EXACTLY 7 global_load_lds per STAGE (6 full + 1 four-lane; masked instrs
// still count in vmcnt). Pipeline per tile: wait vmcnt(7) [loads from 2 tiles
// ago] -> s_barrier -> STAGE(t+2) -> compute(t). 3-buffer ring makes the
// single barrier race-free: a wave in iter t+1 implies all waves finished
// compute(t). No vmcnt(0) drain in the main loop (T4).
__global__ __launch_bounds__(256, 2) void attn(
    const short* __restrict__ Qp, const short* __restrict__ Kp,
    const short* __restrict__ Vt, short* __restrict__ Aproj) {
  __shared__ __align__(16) short KV[3][TCH * 8];  // 3 x 24.25 KB
  int blk = blockIdx.x;
  blk = (blk & 7) * 64 + (blk >> 3);
  const int qt = blk & 15;
  const int h = (blk >> 4) & 15;
  const int b = blk >> 8;
  const int t = threadIdx.x, lane = t & 63, wid = t >> 6;
  const int fr = lane & 15, fq = lane >> 4;

  const long bh = (long)(b * NH + h);
  const short* Qg = Qp + (bh * N_ + qt * 128) * HDP;
  const short* Kg = Kp + bh * N_ * HDP;
  const short* Vg = Vt + bh * HDV * N_;

  // per-lane staging sources: chunk g -> (tile-0 address, per-tile stride)
  const short* sb[7];
  int sstr[7];
  #pragma unroll
  for (int it = 0; it < 7; ++it) {
    int g = wid * WCH + (it < 6 ? it * 64 + lane : 384 + lane);
    if (g >= TCH) g = TCH - 1;  // inactive lanes of it=6 (masked at issue)
    if (g < KCH) {
      const int r = g / 13, c = g - r * 13;
      sb[it] = Kg + r * HDP + (c < 12 ? c * 8 : 0);
      sstr[it] = KVB * HDP;
    } else {
      const int v = g - KCH;
      const int r = v / 9, c = v - r * 9;
      sb[it] = Vg + r * N_ + (c < 8 ? c * 8 : 0);
      sstr[it] = KVB;
    }
  }

  bf16x8 qf[2][3];
  #pragma unroll
  for (int i = 0; i < 2; ++i)
    #pragma unroll
    for (int kk = 0; kk < 3; ++kk)
      qf[i][kk] = *(const bf16x8*)(Qg + (wid * 32 + i * 16 + fr) * HDP + kk * 32 + fq * 8);

  f32x4 accO[2][5] = {};
  float l_[2] = {0.f, 0.f};

  auto STAGE = [&](int kt, int bufi) {
    short* D = &KV[bufi][0];
    #pragma unroll
    for (int it = 0; it < 6; ++it)
      gload_lds16(sb[it] + kt * sstr[it], D + (wid * WCH + it * 64 + lane) * 8);
    if (lane < 4)
      gload_lds16(sb[6] + kt * sstr[6], D + (wid * WCH + 384 + lane) * 8);
  };

  STAGE(0, 0);
  STAGE(1, 1);

  for (int kt = 0; kt < 32; ++kt) {
    if (kt < 31) asm volatile("s_waitcnt vmcnt(7)" ::: "memory");
    else         asm volatile("s_waitcnt vmcnt(0)" ::: "memory");
    __builtin_amdgcn_s_barrier();
    if (kt < 30) STAGE(kt + 2, (kt + 2) % 3);

    const short* KsC = &KV[kt % 3][0];
    const short* VsC = KsC + KCH * 8;

    f32x4 s[2][4] = {};
    __builtin_amdgcn_s_setprio(1);
    #pragma unroll
    for (int j = 0; j < 4; ++j) {
      #pragma unroll
      for (int kk = 0; kk < 3; ++kk) {
        bf16x8 kf = *(const bf16x8*)(KsC + (j * 16 + fr) * KROW + (kk * 4 + fq) * 8);
        s[0][j] = __builtin_amdgcn_mfma_f32_16x16x32_bf16(kf, qf[0][kk], s[0][j], 0, 0, 0);
        s[1][j] = __builtin_amdgcn_mfma_f32_16x16x32_bf16(kf, qf[1][kk], s[1][j], 0, 0, 0);
      }
    }
    __builtin_amdgcn_s_setprio(0);

    #pragma unroll
    for (int i = 0; i < 2; ++i) {
      float psum = 0.f;
      #pragma unroll
      for (int j = 0; j < 4; ++j)
        #pragma unroll
        for (int r = 0; r < 4; ++r) {
          const float p = __builtin_amdgcn_exp2f(s[i][j][r]);
          s[i][j][r] = p;
          psum += p;
        }
      l_[i] += psum;
    }

    __builtin_amdgcn_s_setprio(1);
    #pragma unroll
    for (int g = 0; g < 2; ++g) {
      union { unsigned u[4]; bf16x8 v; } pf0, pf1;
      pf0.u[0] = pack_bf16(s[0][2 * g][0],     s[0][2 * g][1]);
      pf0.u[1] = pack_bf16(s[0][2 * g][2],     s[0][2 * g][3]);
      pf0.u[2] = pack_bf16(s[0][2 * g + 1][0], s[0][2 * g + 1][1]);
      pf0.u[3] = pack_bf16(s[0][2 * g + 1][2], s[0][2 * g + 1][3]);
      pf1.u[0] = pack_bf16(s[1][2 * g][0],     s[1][2 * g][1]);
      pf1.u[1] = pack_bf16(s[1][2 * g][2],     s[1][2 * g][3]);
      pf1.u[2] = pack_bf16(s[1][2 * g + 1][0], s[1][2 * g + 1][1]);
      pf1.u[3] = pack_bf16(s[1][2 * g + 1][2], s[1][2 * g + 1][3]);
      #pragma unroll
      for (int jd = 0; jd < 5; ++jd) {
        bf16x8 vf = *(const bf16x8*)(VsC + (jd * 16 + fr) * VROW + (g * 4 + fq) * 8);
        accO[0][jd] = __builtin_amdgcn_mfma_f32_16x16x32_bf16(pf0.v, vf, accO[0][jd], 0, 0, 0);
        accO[1][jd] = __builtin_amdgcn_mfma_f32_16x16x32_bf16(pf1.v, vf, accO[1][jd], 0, 0, 0);
      }
    }
    __builtin_amdgcn_s_setprio(0);
  }

  #pragma unroll
  for (int i = 0; i < 2; ++i) {
    l_[i] += __shfl_xor(l_[i], 16);
    l_[i] += __shfl_xor(l_[i], 32);
  }
  float linv[2] = {1.f / l_[0], 1.f / l_[1]};
  #pragma unroll
  for (int i = 0; i < 2; ++i) {
    float li[4];
    #pragma unroll
    for (int r = 0; r < 4; ++r) li[r] = __shfl(linv[i], fq * 4 + r);
    #pragma unroll
    for (int r = 0; r < 4; ++r) {
      const long n = qt * 128 + wid * 32 + i * 16 + fq * 4 + r;
      #pragma unroll
      for (int jd = 0; jd < 5; ++jd) {
        const int d = jd * 16 + fr;
        if (d < HD)
          Aproj[((long)b * N_ + n) * C_ + h * HD + d] = f2bf(accO[i][jd][r] * li[r]);
      }
    }
  }
}

extern "C" void kernel_launch(void* const* d_in, const int* in_sizes, int n_in,
                              void* d_out, int out_size, void* d_ws, size_t ws_size,
                              hipStream_t stream) {
  const float* x     = (const float*)d_in[0];
  const float* Wqkv  = (const float*)d_in[1];
  const float* Wproj = (const float*)d_in[2];
  const float* bproj = (const float*)d_in[3];
  float* out = (float*)d_out;

  char* ws = (char*)d_ws;
  short* QKVb = (short*)ws;         size_t off = (size_t)4096 * QSTR * 2;
  short* xb  = (short*)(ws + off);  off += (size_t)4096 * 1152 * 2;
  short* Wt  = (short*)(ws + off);  off += (size_t)QSTR * 1152 * 2;
  short* Wpt = (short*)(ws + off);  off += (size_t)1152 * 1152 * 2;
  short* Qp  = (short*)(ws + off);  off += (size_t)B_ * NH * N_ * HDP * 2;
  short* Kp  = (short*)(ws + off);  off += (size_t)B_ * NH * N_ * HDP * 2;
  short* Vt  = (short*)(ws + off);  off += (size_t)B_ * NH * HDV * N_ * 2;
  short* Ap  = (short*)(ws + off);  off += (size_t)4096 * 1152 * 2;

  prep<<<4608 + 4032 + 1296, 256, 0, stream>>>(x, xb, Wqkv, Wt, Wproj, Wpt);
  gemm_bt256<<<dim3(QSTR / 256, 4096 / 256), 512, 0, stream>>>(
      xb, Wt, QKVb, 4096, QSTR, 1152);
  rope_pack<<<B_ * NH * (N_ / 128), 256, 0, stream>>>(QKVb, Qp, Kp, Vt);
  attn<<<B_ * NH * (N_ / 128), 256, 0, stream>>>(Qp, Kp, Vt, Ap);
  gemm_bt<true, false><<<dim3(1152 / 128, 4096 / 128), 256, 0, stream>>>(
      Ap, Wpt, (void*)out, bproj, 4096, 1152, 1152);
}